// Round 5
// baseline (74.078 us; speedup 1.0000x reference)
//
#include <hip/hip_runtime.h>
#include <hip/hip_bf16.h>

// Problem constants
#define TT 2048
#define BB 4
#define CC 512
#define HH 16
#define KK 31
#define PP 15
#define MM (TT*BB)      // 8192 rows
#define NPAD 512        // HK=496 padded to 512 (pad rows of Wl are zero)

typedef __bf16 bf16x8 __attribute__((ext_vector_type(8)));
typedef float f32x4 __attribute__((ext_vector_type(4)));
typedef unsigned short ushort8 __attribute__((ext_vector_type(8)));
typedef unsigned short ushort4v __attribute__((ext_vector_type(4)));

__device__ __forceinline__ float bf2f(unsigned short u) {
    return __uint_as_float(((unsigned int)u) << 16);
}
__device__ __forceinline__ unsigned short f2bf(float f) {
    unsigned int x = __float_as_uint(f);
    x += 0x7fffu + ((x >> 16) & 1u);
    return (unsigned short)(x >> 16);
}

// ---------------------------------------------------------------------------
// cast fp32 -> bf16 for x (4 elems/thread)
// ---------------------------------------------------------------------------
__global__ __launch_bounds__(256) void cast_x(const float* __restrict__ src,
                                              unsigned short* __restrict__ dst) {
    const int i = (blockIdx.x * 256 + threadIdx.x) * 4;
    const float4 v = *(const float4*)&src[i];
    ushort4v o = { f2bf(v.x), f2bf(v.y), f2bf(v.z), f2bf(v.w) };
    *(ushort4v*)&dst[i] = o;
}

// ---------------------------------------------------------------------------
// cast all three weight matrices in one dispatch (768 blocks x 1024 elems).
// Wl rows 496..511 are zero-padded.
// ---------------------------------------------------------------------------
__global__ __launch_bounds__(256) void cast_weights(const float* __restrict__ W1,
                                                    const float* __restrict__ Wl,
                                                    const float* __restrict__ W2,
                                                    unsigned short* __restrict__ W1b,
                                                    unsigned short* __restrict__ Wlb,
                                                    unsigned short* __restrict__ W2b) {
    const int b = blockIdx.x;
    const int i = (b & 255) * 1024 + threadIdx.x * 4;
    const float* src;
    unsigned short* dst;
    int n_src = 262144;
    if (b < 256)      { src = W1; dst = W1b; }
    else if (b < 512) { src = Wl; dst = Wlb; n_src = HH * KK * CC; }
    else              { src = W2; dst = W2b; }
    ushort4v o = {0, 0, 0, 0};
    if (i < n_src) {
        const float4 v = *(const float4*)&src[i];
        o[0] = f2bf(v.x); o[1] = f2bf(v.y); o[2] = f2bf(v.z); o[3] = f2bf(v.w);
    }
    *(ushort4v*)&dst[i] = o;
}

// ---------------------------------------------------------------------------
// bf16 MFMA GEMM-NT (m97 structure): C[m,n] = sum_k A[m,k]*B[n,k] (+bias[n])
// 128x128 tile, BK=32, 256 thr = 4 waves (2x2), each wave 64x64 out
// (4x4 fragments of 16x16x32). global_load_lds width=16, linear LDS dest +
// pre-swizzled global source; ds_read applies the same swizzle.
// Staging: each 128x32 tile = 512 x 16B slots = 2 rounds of 256 thr x 16B.
// 1D grid with chunked XCD swizzle (gridDim.x % 8 == 0).
// M%128==0, N%128==0, K%32==0.
// ---------------------------------------------------------------------------
#define GBM 128
#define GBN 128
#define GBK 32

template<bool OUT_BF16>
__global__ __launch_bounds__(256, 2) void gemm_nt_mfma(const unsigned short* __restrict__ A,
                                                       const unsigned short* __restrict__ B,
                                                       const float* __restrict__ bias,
                                                       void* __restrict__ Cout,
                                                       int N, int Kc, int nn) {
    __shared__ short As[GBM * GBK];   // 8 KB
    __shared__ short Bs[GBN * GBK];   // 8 KB

    const int tid = threadIdx.x;
    const int l   = tid & 63;
    const int wv  = tid >> 6;      // wave 0..3
    const int wr  = wv >> 1;       // wave row (0..1) -> 64 rows
    const int wc  = wv & 1;        // wave col (0..1) -> 64 cols

    // chunked XCD swizzle: XCD x owns a contiguous run of tiles
    const int s  = (blockIdx.x & 7) * (gridDim.x >> 3) + (blockIdx.x >> 3);
    const int bm = (s / nn) * GBM;
    const int bn = (s % nn) * GBN;

    // 2 staging rounds per matrix: round j covers rows [j*64, j*64+64).
    // Linear LDS dest (wave-uniform base + lane*16B); source slot
    // pre-swizzled (slot' = slot ^ ((row>>1)&3)) to match swizzled ds_read.
    const unsigned short* gA[2];
    const unsigned short* gB[2];
    #pragma unroll
    for (int j = 0; j < 2; ++j) {
        const int idx16 = j * 256 + tid;
        const int r  = idx16 >> 2;
        const int sl = (idx16 & 3) ^ ((r >> 1) & 3);
        gA[j] = A + (size_t)(bm + r) * Kc + sl * 8;
        gB[j] = B + (size_t)(bn + r) * Kc + sl * 8;
    }

    f32x4 acc[4][4] = {};

    const int lr = l & 15;     // fragment row-within-16
    const int ls = l >> 4;     // k-slot 0..3 (8 bf16 each)
    int offA[4], offB[4];
    #pragma unroll
    for (int mi = 0; mi < 4; ++mi) {
        const int r = wr * 64 + mi * 16 + lr;
        offA[mi] = r * 32 + ((ls ^ ((r >> 1) & 3)) * 8);
    }
    #pragma unroll
    for (int ni = 0; ni < 4; ++ni) {
        const int r = wc * 64 + ni * 16 + lr;
        offB[ni] = r * 32 + ((ls ^ ((r >> 1) & 3)) * 8);
    }

    for (int k0 = 0; k0 < Kc; k0 += GBK) {
        #pragma unroll
        for (int j = 0; j < 2; ++j) {
            __builtin_amdgcn_global_load_lds((const __attribute__((address_space(1))) void*)(gA[j] + k0),
                                             (__attribute__((address_space(3))) void*)(As + j * 2048 + wv * 512), 16, 0, 0);
            __builtin_amdgcn_global_load_lds((const __attribute__((address_space(1))) void*)(gB[j] + k0),
                                             (__attribute__((address_space(3))) void*)(Bs + j * 2048 + wv * 512), 16, 0, 0);
        }
        __syncthreads();   // compiler drains vmcnt before s_barrier

        bf16x8 af[4], bfv[4];
        #pragma unroll
        for (int mi = 0; mi < 4; ++mi) af[mi] = *(const bf16x8*)&As[offA[mi]];
        #pragma unroll
        for (int ni = 0; ni < 4; ++ni) bfv[ni] = *(const bf16x8*)&Bs[offB[ni]];

        #pragma unroll
        for (int mi = 0; mi < 4; ++mi)
            #pragma unroll
            for (int ni = 0; ni < 4; ++ni)
                acc[mi][ni] = __builtin_amdgcn_mfma_f32_16x16x32_bf16(af[mi], bfv[ni], acc[mi][ni], 0, 0, 0);
        __syncthreads();
    }

    // C/D layout (m89): col = lane&15, row = (lane>>4)*4 + j
    #pragma unroll
    for (int mi = 0; mi < 4; ++mi) {
        const int row0 = bm + wr * 64 + mi * 16 + ls * 4;
        #pragma unroll
        for (int ni = 0; ni < 4; ++ni) {
            const int col = bn + wc * 64 + ni * 16 + lr;
            const float bv = bias ? bias[col] : 0.0f;
            #pragma unroll
            for (int j = 0; j < 4; ++j) {
                const float v = acc[mi][ni][j] + bv;
                if (OUT_BF16)
                    ((unsigned short*)Cout)[(size_t)(row0 + j) * N + col] = f2bf(v);
                else
                    ((float*)Cout)[(size_t)(row0 + j) * N + col] = v;
            }
        }
    }
}

// ---------------------------------------------------------------------------
// Fused softmax + dynamic conv. One block per t (all 4 b, all 512 c).
// Phase 1: 64 softmax rows (b,head) from raw logits -> LDS [64][32] fp32.
// Phase 2: thread = (b, c0=8ch): 31-tap conv, h via L2 (XCD chunked swizzle),
//          weights broadcast from LDS. bf16 out.
// ---------------------------------------------------------------------------
__global__ __launch_bounds__(256) void dynconv_fused(const unsigned short* __restrict__ hb,
                                                     const float* __restrict__ logits,
                                                     unsigned short* __restrict__ cvb) {
    __shared__ float w_s[64][32];   // 8 KB

    const int bid = blockIdx.x;
    const int t   = (bid & 7) * 256 + (bid >> 3);
    const int tid = threadIdx.x;

    // ---- Phase 1: softmax over K=31 for 64 rows, 4 lanes each ----
    {
        const int r = tid >> 2;          // row 0..63: b = r>>4, head = r&15
        const int q = tid & 3;           // lane-in-group
        const int b = r >> 4, hd = r & 15;
        const float* lp = logits + (size_t)(t * BB + b) * NPAD + hd * KK;
        float e[8];
        const int k0 = q * 8;
        const int kn = (q == 3) ? 7 : 8;
        float mx = -1e30f;
        #pragma unroll
        for (int j = 0; j < 8; ++j) {
            e[j] = (j < kn) ? lp[k0 + j] : -1e30f;
            mx = fmaxf(mx, e[j]);
        }
        mx = fmaxf(mx, __shfl_xor(mx, 1, 4));
        mx = fmaxf(mx, __shfl_xor(mx, 2, 4));
        float sm = 0.f;
        #pragma unroll
        for (int j = 0; j < 8; ++j) {
            e[j] = (j < kn) ? __expf(e[j] - mx) : 0.f;
            sm += e[j];
        }
        sm += __shfl_xor(sm, 1, 4);
        sm += __shfl_xor(sm, 2, 4);
        const float inv = 1.f / sm;
        #pragma unroll
        for (int j = 0; j < 8; ++j)
            if (j < kn) w_s[r][k0 + j] = e[j] * inv;
    }
    __syncthreads();

    // ---- Phase 2: conv ----
    const int c0 = (tid & 63) * 8;       // channel group; wave = one b
    const int b  = tid >> 6;
    const int wrow = b * 16 + (c0 >> 5); // (b, head)
    float acc[8] = {};
    #pragma unroll
    for (int k = 0; k < KK; ++k) {
        const int tt = t - PP + k;
        if ((unsigned)tt >= TT) continue;
        const ushort8 hv = *(const ushort8*)&hb[(size_t)((tt * BB + b) * CC) + c0];
        const float wk = w_s[wrow][k];
        #pragma unroll
        for (int j = 0; j < 8; ++j) acc[j] = fmaf(bf2f(hv[j]), wk, acc[j]);
    }
    ushort8 o;
    #pragma unroll
    for (int j = 0; j < 8; ++j) o[j] = f2bf(acc[j]);
    *(ushort8*)&cvb[(size_t)((t * BB + b) * CC) + c0] = o;
}

extern "C" void kernel_launch(void* const* d_in, const int* in_sizes, int n_in,
                              void* d_out, int out_size, void* d_ws, size_t ws_size,
                              hipStream_t stream) {
    const float* x  = (const float*)d_in[0];
    const float* W1 = (const float*)d_in[1];
    const float* b1 = (const float*)d_in[2];
    const float* Wl = (const float*)d_in[3];
    const float* W2 = (const float*)d_in[4];
    const float* b2 = (const float*)d_in[5];
    float* out = (float*)d_out;

    // workspace layout
    unsigned short* xb  = (unsigned short*)d_ws;             // 8 MB
    unsigned short* hb  = xb  + (size_t)MM * CC;             // 8 MB
    unsigned short* cvb = hb  + (size_t)MM * CC;             // 8 MB
    unsigned short* W1b = cvb + (size_t)MM * CC;             // 0.5 MB
    unsigned short* Wlb = W1b + (size_t)CC * CC;             // 0.5 MB (padded)
    unsigned short* W2b = Wlb + (size_t)NPAD * CC;           // 0.5 MB
    float*          wgt = (float*)(W2b + (size_t)CC * CC);   // 16 MB fp32 logits

    const int nxc = MM * CC;           // 4194304

    cast_x<<<nxc / 1024, 256, 0, stream>>>(x, xb);
    cast_weights<<<768, 256, 0, stream>>>(W1, Wl, W2, W1b, Wlb, W2b);

    const int nblk = (MM / GBM) * (CC / GBN);   // 64 * 4 = 256

    // 1) h = x @ W1^T + b1   (bf16 out)
    gemm_nt_mfma<true><<<nblk, 256, 0, stream>>>(xb, W1b, b1, hb, CC, CC, CC / GBN);
    // 2) logits = h @ Wl^T   (fp32 out, padded N)
    gemm_nt_mfma<false><<<nblk, 256, 0, stream>>>(hb, Wlb, nullptr, wgt, NPAD, CC, NPAD / GBN);
    // 3+4) fused softmax + dynamic conv (bf16 out)
    dynconv_fused<<<TT, 256, 0, stream>>>(hb, wgt, cvb);
    // 5) out = cv @ W2^T + b2  (fp32 out)
    gemm_nt_mfma<false><<<nblk, 256, 0, stream>>>(cvb, W2b, b2, out, CC, CC, CC / GBN);
}

// Round 6
// 60.613 us; speedup vs baseline: 1.2221x; 1.2221x over previous
//
#include <hip/hip_runtime.h>
#include <hip/hip_bf16.h>

// Problem constants
#define TT 2048
#define BB 4
#define CC 512
#define HH 16
#define KK 31
#define PP 15
#define MM (TT*BB)      // 8192 rows
#define NPAD 512        // HK=496 padded to 512 (pad rows of Wl are zero)

typedef __bf16 bf16x8 __attribute__((ext_vector_type(8)));
typedef float f32x4 __attribute__((ext_vector_type(4)));
typedef unsigned short ushort8 __attribute__((ext_vector_type(8)));
typedef unsigned short ushort4v __attribute__((ext_vector_type(4)));

__device__ __forceinline__ float bf2f(unsigned short u) {
    return __uint_as_float(((unsigned int)u) << 16);
}
__device__ __forceinline__ unsigned short f2bf(float f) {
    unsigned int x = __float_as_uint(f);
    x += 0x7fffu + ((x >> 16) & 1u);
    return (unsigned short)(x >> 16);
}

// ---------------------------------------------------------------------------
// cast fp32 -> bf16 for x (4 elems/thread)
// ---------------------------------------------------------------------------
__global__ __launch_bounds__(256) void cast_x(const float* __restrict__ src,
                                              unsigned short* __restrict__ dst) {
    const int i = (blockIdx.x * 256 + threadIdx.x) * 4;
    const float4 v = *(const float4*)&src[i];
    ushort4v o = { f2bf(v.x), f2bf(v.y), f2bf(v.z), f2bf(v.w) };
    *(ushort4v*)&dst[i] = o;
}

// ---------------------------------------------------------------------------
// cast all three weight matrices in one dispatch (768 blocks x 1024 elems).
// Wl rows 496..511 are zero-padded.
// ---------------------------------------------------------------------------
__global__ __launch_bounds__(256) void cast_weights(const float* __restrict__ W1,
                                                    const float* __restrict__ Wl,
                                                    const float* __restrict__ W2,
                                                    unsigned short* __restrict__ W1b,
                                                    unsigned short* __restrict__ Wlb,
                                                    unsigned short* __restrict__ W2b) {
    const int b = blockIdx.x;
    const int i = (b & 255) * 1024 + threadIdx.x * 4;
    const float* src;
    unsigned short* dst;
    int n_src = 262144;
    if (b < 256)      { src = W1; dst = W1b; }
    else if (b < 512) { src = Wl; dst = Wlb; n_src = HH * KK * CC; }
    else              { src = W2; dst = W2b; }
    ushort4v o = {0, 0, 0, 0};
    if (i < n_src) {
        const float4 v = *(const float4*)&src[i];
        o[0] = f2bf(v.x); o[1] = f2bf(v.y); o[2] = f2bf(v.z); o[3] = f2bf(v.w);
    }
    *(ushort4v*)&dst[i] = o;
}

// ---------------------------------------------------------------------------
// bf16 MFMA GEMM-NT, double-buffered: C[m,n] = sum_k A[m,k]*B[n,k] (+bias[n])
// 128x64 tile, BK=64, 256 thr = 4 waves (2x2), each wave 64x32 out.
// Per K-step: issue next tile's global_load_lds FIRST, then ds_read+MFMA on
// current buffer, then one __syncthreads (its vmcnt drain lands AFTER the
// compute -> prefetch latency hidden). 512 blocks -> 2 blocks/CU.
// LDS swizzle: slot' = slot ^ (row&7) (8 slots/row of 16B), both sides.
// M%128==0, N%64==0, K%64==0.
// ---------------------------------------------------------------------------
#define GBM 128
#define GBN 64
#define GBK 64

template<bool OUT_BF16>
__global__ __launch_bounds__(256, 2) void gemm_nt_mfma(const unsigned short* __restrict__ A,
                                                       const unsigned short* __restrict__ B,
                                                       const float* __restrict__ bias,
                                                       void* __restrict__ Cout,
                                                       int N, int Kc, int nn) {
    __shared__ short As[2][GBM * GBK];   // 2 x 16 KB
    __shared__ short Bs[2][GBN * GBK];   // 2 x 8 KB

    const int tid = threadIdx.x;
    const int l   = tid & 63;
    const int wv  = tid >> 6;      // wave 0..3
    const int wr  = wv >> 1;       // wave row (0..1) -> 64 rows
    const int wc  = wv & 1;        // wave col (0..1) -> 32 cols

    // chunked XCD swizzle; consecutive s share an m-tile (A panel reuse in L2)
    const int s  = (blockIdx.x & 7) * (gridDim.x >> 3) + (blockIdx.x >> 3);
    const int bm = (s / nn) * GBM;
    const int bn = (s % nn) * GBN;

    // Staging: A tile 128 rows x 8 slots(16B) = 1024 slots = 4 rounds x 256thr;
    // B tile 64 x 8 = 512 slots = 2 rounds. Linear LDS dest; global source
    // slot pre-swizzled: slot' = slot ^ (row&7)  (involution).
    const unsigned short* gA[4];
    const unsigned short* gB[2];
    #pragma unroll
    for (int j = 0; j < 4; ++j) {
        const int idx16 = j * 256 + tid;
        const int r  = idx16 >> 3;
        const int sl = (idx16 & 7) ^ (r & 7);
        gA[j] = A + (size_t)(bm + r) * Kc + sl * 8;
    }
    #pragma unroll
    for (int j = 0; j < 2; ++j) {
        const int idx16 = j * 256 + tid;
        const int r  = idx16 >> 3;
        const int sl = (idx16 & 7) ^ (r & 7);
        gB[j] = B + (size_t)(bn + r) * Kc + sl * 8;
    }

    f32x4 acc[4][2] = {};

    const int lr = l & 15;     // fragment row-within-16
    const int ls = l >> 4;     // k-slot-within-32k (8 bf16 each)
    // LDS offsets (shorts) for fragment reads, swizzled
    int offA[4][2], offB[2][2];
    #pragma unroll
    for (int mi = 0; mi < 4; ++mi) {
        const int r = wr * 64 + mi * 16 + lr;
        #pragma unroll
        for (int ks = 0; ks < 2; ++ks)
            offA[mi][ks] = r * 64 + (((ks * 4 + ls) ^ (r & 7)) * 8);
    }
    #pragma unroll
    for (int ni = 0; ni < 2; ++ni) {
        const int r = wc * 32 + ni * 16 + lr;
        #pragma unroll
        for (int ks = 0; ks < 2; ++ks)
            offB[ni][ks] = r * 64 + (((ks * 4 + ls) ^ (r & 7)) * 8);
    }

    const int NT = Kc / GBK;

    // prologue: stage tile 0 into buf 0
    #pragma unroll
    for (int j = 0; j < 4; ++j)
        __builtin_amdgcn_global_load_lds((const __attribute__((address_space(1))) void*)(gA[j]),
                                         (__attribute__((address_space(3))) void*)(&As[0][0] + j * 2048 + wv * 512), 16, 0, 0);
    #pragma unroll
    for (int j = 0; j < 2; ++j)
        __builtin_amdgcn_global_load_lds((const __attribute__((address_space(1))) void*)(gB[j]),
                                         (__attribute__((address_space(3))) void*)(&Bs[0][0] + j * 2048 + wv * 512), 16, 0, 0);
    __syncthreads();

    int cur = 0;
    for (int kt = 0; kt < NT; ++kt) {
        // 1) issue next tile's loads into the other buffer (async)
        if (kt + 1 < NT) {
            const int k0 = (kt + 1) * GBK;
            #pragma unroll
            for (int j = 0; j < 4; ++j)
                __builtin_amdgcn_global_load_lds((const __attribute__((address_space(1))) void*)(gA[j] + k0),
                                                 (__attribute__((address_space(3))) void*)(&As[cur ^ 1][0] + j * 2048 + wv * 512), 16, 0, 0);
            #pragma unroll
            for (int j = 0; j < 2; ++j)
                __builtin_amdgcn_global_load_lds((const __attribute__((address_space(1))) void*)(gB[j] + k0),
                                                 (__attribute__((address_space(3))) void*)(&Bs[cur ^ 1][0] + j * 2048 + wv * 512), 16, 0, 0);
        }

        // 2) compute on current buffer
        bf16x8 af[4][2], bfv[2][2];
        #pragma unroll
        for (int mi = 0; mi < 4; ++mi)
            #pragma unroll
            for (int ks = 0; ks < 2; ++ks)
                af[mi][ks] = *(const bf16x8*)&As[cur][offA[mi][ks]];
        #pragma unroll
        for (int ni = 0; ni < 2; ++ni)
            #pragma unroll
            for (int ks = 0; ks < 2; ++ks)
                bfv[ni][ks] = *(const bf16x8*)&Bs[cur][offB[ni][ks]];

        #pragma unroll
        for (int mi = 0; mi < 4; ++mi)
            #pragma unroll
            for (int ni = 0; ni < 2; ++ni)
                #pragma unroll
                for (int ks = 0; ks < 2; ++ks)
                    acc[mi][ni] = __builtin_amdgcn_mfma_f32_16x16x32_bf16(af[mi][ks], bfv[ni][ks], acc[mi][ni], 0, 0, 0);

        // 3) single barrier: drains prefetch (hidden under compute) + syncs
        __syncthreads();
        cur ^= 1;
    }

    // C/D layout (m89): col = lane&15, row = (lane>>4)*4 + j
    #pragma unroll
    for (int mi = 0; mi < 4; ++mi) {
        const int row0 = bm + wr * 64 + mi * 16 + ls * 4;
        #pragma unroll
        for (int ni = 0; ni < 2; ++ni) {
            const int col = bn + wc * 32 + ni * 16 + lr;
            const float bv = bias ? bias[col] : 0.0f;
            #pragma unroll
            for (int j = 0; j < 4; ++j) {
                const float v = acc[mi][ni][j] + bv;
                if (OUT_BF16)
                    ((unsigned short*)Cout)[(size_t)(row0 + j) * N + col] = f2bf(v);
                else
                    ((float*)Cout)[(size_t)(row0 + j) * N + col] = v;
            }
        }
    }
}

// ---------------------------------------------------------------------------
// Fused softmax + dynamic conv. One block per t (all 4 b, all 512 c).
// Phase 1: 64 softmax rows (b,head) from bf16 logits -> LDS [64][33] fp32
//          (pad 33: wave reads 16 distinct wrows, stride 132B -> 16 banks).
// Phase 2: thread = (b, c0=8ch): 31-tap conv, h via L2 (XCD chunked swizzle),
//          weights broadcast from LDS. bf16 out.
// ---------------------------------------------------------------------------
__global__ __launch_bounds__(256) void dynconv_fused(const unsigned short* __restrict__ hb,
                                                     const unsigned short* __restrict__ logits,
                                                     unsigned short* __restrict__ cvb) {
    __shared__ float w_s[64][33];   // padded

    const int bid = blockIdx.x;
    const int t   = (bid & 7) * 256 + (bid >> 3);
    const int tid = threadIdx.x;

    // ---- Phase 1: softmax over K=31 for 64 rows, 4 lanes each ----
    {
        const int r = tid >> 2;          // row 0..63: b = r>>4, head = r&15
        const int q = tid & 3;           // lane-in-group
        const int b = r >> 4, hd = r & 15;
        const unsigned short* lp = logits + (size_t)(t * BB + b) * NPAD + hd * KK;
        float e[8];
        const int k0 = q * 8;
        const int kn = (q == 3) ? 7 : 8;
        float mx = -1e30f;
        #pragma unroll
        for (int j = 0; j < 8; ++j) {
            e[j] = (j < kn) ? bf2f(lp[k0 + j]) : -1e30f;
            mx = fmaxf(mx, e[j]);
        }
        mx = fmaxf(mx, __shfl_xor(mx, 1, 4));
        mx = fmaxf(mx, __shfl_xor(mx, 2, 4));
        float sm = 0.f;
        #pragma unroll
        for (int j = 0; j < 8; ++j) {
            e[j] = (j < kn) ? __expf(e[j] - mx) : 0.f;
            sm += e[j];
        }
        sm += __shfl_xor(sm, 1, 4);
        sm += __shfl_xor(sm, 2, 4);
        const float inv = 1.f / sm;
        #pragma unroll
        for (int j = 0; j < 8; ++j)
            if (j < kn) w_s[r][k0 + j] = e[j] * inv;
    }
    __syncthreads();

    // ---- Phase 2: conv ----
    const int c0 = (tid & 63) * 8;       // channel group; wave = one b
    const int b  = tid >> 6;
    const int wrow = b * 16 + (c0 >> 5); // (b, head)
    float acc[8] = {};
    #pragma unroll
    for (int k = 0; k < KK; ++k) {
        const int tt = t - PP + k;
        if ((unsigned)tt >= TT) continue;
        const ushort8 hv = *(const ushort8*)&hb[(size_t)((tt * BB + b) * CC) + c0];
        const float wk = w_s[wrow][k];
        #pragma unroll
        for (int j = 0; j < 8; ++j) acc[j] = fmaf(bf2f(hv[j]), wk, acc[j]);
    }
    ushort8 o;
    #pragma unroll
    for (int j = 0; j < 8; ++j) o[j] = f2bf(acc[j]);
    *(ushort8*)&cvb[(size_t)((t * BB + b) * CC) + c0] = o;
}

extern "C" void kernel_launch(void* const* d_in, const int* in_sizes, int n_in,
                              void* d_out, int out_size, void* d_ws, size_t ws_size,
                              hipStream_t stream) {
    const float* x  = (const float*)d_in[0];
    const float* W1 = (const float*)d_in[1];
    const float* b1 = (const float*)d_in[2];
    const float* Wl = (const float*)d_in[3];
    const float* W2 = (const float*)d_in[4];
    const float* b2 = (const float*)d_in[5];
    float* out = (float*)d_out;

    // workspace layout (all bf16 except out)
    unsigned short* xb  = (unsigned short*)d_ws;             // 8 MB
    unsigned short* hb  = xb  + (size_t)MM * CC;             // 8 MB
    unsigned short* cvb = hb  + (size_t)MM * CC;             // 8 MB
    unsigned short* W1b = cvb + (size_t)MM * CC;             // 0.5 MB
    unsigned short* Wlb = W1b + (size_t)CC * CC;             // 0.5 MB (padded)
    unsigned short* W2b = Wlb + (size_t)NPAD * CC;           // 0.5 MB
    unsigned short* lgb = W2b + (size_t)CC * CC;             // 8 MB bf16 logits

    const int nxc = MM * CC;           // 4194304

    cast_x<<<nxc / 1024, 256, 0, stream>>>(x, xb);
    cast_weights<<<768, 256, 0, stream>>>(W1, Wl, W2, W1b, Wlb, W2b);

    const int nblk = (MM / GBM) * (CC / GBN);   // 64 * 8 = 512

    // 1) h = x @ W1^T + b1   (bf16 out)
    gemm_nt_mfma<true><<<nblk, 256, 0, stream>>>(xb, W1b, b1, hb, CC, CC, CC / GBN);
    // 2) logits = h @ Wl^T   (bf16 out, padded N)
    gemm_nt_mfma<true><<<nblk, 256, 0, stream>>>(hb, Wlb, nullptr, lgb, NPAD, CC, NPAD / GBN);
    // 3+4) fused softmax + dynamic conv (bf16 out)
    dynconv_fused<<<TT, 256, 0, stream>>>(hb, lgb, cvb);
    // 5) out = cv @ W2^T + b2  (fp32 out)
    gemm_nt_mfma<false><<<nblk, 256, 0, stream>>>(cvb, W2b, b2, out, CC, CC, CC / GBN);
}

// Round 7
// 55.657 us; speedup vs baseline: 1.3310x; 1.0890x over previous
//
#include <hip/hip_runtime.h>
#include <hip/hip_bf16.h>

// Problem constants
#define TT 2048
#define BB 4
#define CC 512
#define HH 16
#define KK 31
#define PP 15
#define MM (TT*BB)      // 8192 rows
#define NPAD 512        // HK=496 padded to 512 (pad rows of Wl are zero)

typedef __bf16 bf16x8 __attribute__((ext_vector_type(8)));
typedef float f32x4 __attribute__((ext_vector_type(4)));
typedef unsigned short ushort8 __attribute__((ext_vector_type(8)));
typedef unsigned short ushort4v __attribute__((ext_vector_type(4)));

__device__ __forceinline__ float bf2f(unsigned short u) {
    return __uint_as_float(((unsigned int)u) << 16);
}
__device__ __forceinline__ unsigned short f2bf(float f) {
    unsigned int x = __float_as_uint(f);
    x += 0x7fffu + ((x >> 16) & 1u);
    return (unsigned short)(x >> 16);
}

// ---------------------------------------------------------------------------
// cast fp32 -> bf16 for x (4 elems/thread)
// ---------------------------------------------------------------------------
__global__ __launch_bounds__(256) void cast_x(const float* __restrict__ src,
                                              unsigned short* __restrict__ dst) {
    const int i = (blockIdx.x * 256 + threadIdx.x) * 4;
    const float4 v = *(const float4*)&src[i];
    ushort4v o = { f2bf(v.x), f2bf(v.y), f2bf(v.z), f2bf(v.w) };
    *(ushort4v*)&dst[i] = o;
}

// ---------------------------------------------------------------------------
// cast all three weight matrices in one dispatch (768 blocks x 1024 elems).
// Wl rows 496..511 are zero-padded.
// ---------------------------------------------------------------------------
__global__ __launch_bounds__(256) void cast_weights(const float* __restrict__ W1,
                                                    const float* __restrict__ Wl,
                                                    const float* __restrict__ W2,
                                                    unsigned short* __restrict__ W1b,
                                                    unsigned short* __restrict__ Wlb,
                                                    unsigned short* __restrict__ W2b) {
    const int b = blockIdx.x;
    const int i = (b & 255) * 1024 + threadIdx.x * 4;
    const float* src;
    unsigned short* dst;
    int n_src = 262144;
    if (b < 256)      { src = W1; dst = W1b; }
    else if (b < 512) { src = Wl; dst = Wlb; n_src = HH * KK * CC; }
    else              { src = W2; dst = W2b; }
    ushort4v o = {0, 0, 0, 0};
    if (i < n_src) {
        const float4 v = *(const float4*)&src[i];
        o[0] = f2bf(v.x); o[1] = f2bf(v.y); o[2] = f2bf(v.z); o[3] = f2bf(v.w);
    }
    *(ushort4v*)&dst[i] = o;
}

// ---------------------------------------------------------------------------
// bf16 MFMA GEMM-NT, 3-stage pipeline with counted vmcnt (T3+T4):
// C[m,n] = sum_k A[m,k]*B[n,k] (+bias[n]); K fixed at 512 (NT=8 x BK=64).
// 128x64 tile, 256 thr = 4 waves (2x2), each wave 64x32 out.
// Per iter t: {vmcnt(6); s_barrier; issue stage(t+2); ds_read+MFMA on buf t%3}.
// vmcnt never drains to 0 in-loop -> prefetch stays in flight across barriers.
// Barrier at top of t follows all waves' compute(t-1), so stage into
// buf[(t+2)%3]==buf[(t-1)%3] cannot race.
// LDS 3*(16+8)=72 KB -> 2 blocks/CU. 512 blocks. Swizzle slot^=(row&7).
// ---------------------------------------------------------------------------
#define GBM 128
#define GBN 64
#define GBK 64
#define KC  512
#define NT  8

#define STAGE(kt, buf)                                                                         \
    do {                                                                                       \
        const int k0_ = (kt) * GBK;                                                            \
        _Pragma("unroll")                                                                      \
        for (int j = 0; j < 4; ++j)                                                            \
            __builtin_amdgcn_global_load_lds(                                                  \
                (const __attribute__((address_space(1))) void*)(gA[j] + k0_),                  \
                (__attribute__((address_space(3))) void*)(&As[buf][0] + j * 2048 + wv * 512),  \
                16, 0, 0);                                                                     \
        _Pragma("unroll")                                                                      \
        for (int j = 0; j < 2; ++j)                                                            \
            __builtin_amdgcn_global_load_lds(                                                  \
                (const __attribute__((address_space(1))) void*)(gB[j] + k0_),                  \
                (__attribute__((address_space(3))) void*)(&Bs[buf][0] + j * 2048 + wv * 512),  \
                16, 0, 0);                                                                     \
    } while (0)

template<bool OUT_BF16>
__global__ __launch_bounds__(256, 2) void gemm_nt_mfma(const unsigned short* __restrict__ A,
                                                       const unsigned short* __restrict__ B,
                                                       const float* __restrict__ bias,
                                                       void* __restrict__ Cout,
                                                       int N, int nn) {
    __shared__ short As[3][GBM * GBK];   // 3 x 16 KB
    __shared__ short Bs[3][GBN * GBK];   // 3 x 8 KB

    const int tid = threadIdx.x;
    const int l   = tid & 63;
    const int wv  = tid >> 6;      // wave 0..3
    const int wr  = wv >> 1;       // wave row (0..1) -> 64 rows
    const int wc  = wv & 1;        // wave col (0..1) -> 32 cols

    // chunked XCD swizzle; consecutive s share A panel in the XCD's L2
    const int s  = (blockIdx.x & 7) * (gridDim.x >> 3) + (blockIdx.x >> 3);
    const int bm = (s / nn) * GBM;
    const int bn = (s % nn) * GBN;

    // Staging addresses: A tile 128 rows x 8 slots(16B) = 4 rounds x 256 thr;
    // B tile 64 x 8 = 2 rounds. Linear LDS dest; source slot pre-swizzled
    // slot' = slot ^ (row&7) (involution, matches swizzled ds_read).
    const unsigned short* gA[4];
    const unsigned short* gB[2];
    #pragma unroll
    for (int j = 0; j < 4; ++j) {
        const int idx16 = j * 256 + tid;
        const int r  = idx16 >> 3;
        const int sl = (idx16 & 7) ^ (r & 7);
        gA[j] = A + (size_t)(bm + r) * KC + sl * 8;
    }
    #pragma unroll
    for (int j = 0; j < 2; ++j) {
        const int idx16 = j * 256 + tid;
        const int r  = idx16 >> 3;
        const int sl = (idx16 & 7) ^ (r & 7);
        gB[j] = B + (size_t)(bn + r) * KC + sl * 8;
    }

    f32x4 acc[4][2] = {};

    const int lr = l & 15;     // fragment row-within-16
    const int ls = l >> 4;     // k-slot-within-32k (8 bf16 each)
    int offA[4][2], offB[2][2];
    #pragma unroll
    for (int mi = 0; mi < 4; ++mi) {
        const int r = wr * 64 + mi * 16 + lr;
        #pragma unroll
        for (int ks = 0; ks < 2; ++ks)
            offA[mi][ks] = r * 64 + (((ks * 4 + ls) ^ (r & 7)) * 8);
    }
    #pragma unroll
    for (int ni = 0; ni < 2; ++ni) {
        const int r = wc * 32 + ni * 16 + lr;
        #pragma unroll
        for (int ks = 0; ks < 2; ++ks)
            offB[ni][ks] = r * 64 + (((ks * 4 + ls) ^ (r & 7)) * 8);
    }

    // prologue: stage tiles 0,1 (12 loads in flight per wave)
    STAGE(0, 0);
    STAGE(1, 1);

    #pragma unroll
    for (int kt = 0; kt < NT; ++kt) {
        // (a) wait: tile kt resident (keep later tiles in flight)
        if (kt < NT - 1) asm volatile("s_waitcnt vmcnt(6)" ::: "memory");
        else             asm volatile("s_waitcnt vmcnt(0)" ::: "memory");
        // (b) all waves: tile kt loaded everywhere, compute(kt-1) done everywhere
        __builtin_amdgcn_s_barrier();
        // (c) prefetch tile kt+2 (overwrites buf[(kt-1)%3], safe after barrier)
        if (kt + 2 < NT) STAGE(kt + 2, (kt + 2) % 3);

        // (d) compute on buf kt%3
        const int cb = kt % 3;
        bf16x8 af[4][2], bfv[2][2];
        #pragma unroll
        for (int mi = 0; mi < 4; ++mi)
            #pragma unroll
            for (int ks = 0; ks < 2; ++ks)
                af[mi][ks] = *(const bf16x8*)&As[cb][offA[mi][ks]];
        #pragma unroll
        for (int ni = 0; ni < 2; ++ni)
            #pragma unroll
            for (int ks = 0; ks < 2; ++ks)
                bfv[ni][ks] = *(const bf16x8*)&Bs[cb][offB[ni][ks]];

        #pragma unroll
        for (int mi = 0; mi < 4; ++mi)
            #pragma unroll
            for (int ni = 0; ni < 2; ++ni)
                #pragma unroll
                for (int ks = 0; ks < 2; ++ks)
                    acc[mi][ni] = __builtin_amdgcn_mfma_f32_16x16x32_bf16(af[mi][ks], bfv[ni][ks], acc[mi][ni], 0, 0, 0);
    }

    // C/D layout (m89): col = lane&15, row = (lane>>4)*4 + j
    #pragma unroll
    for (int mi = 0; mi < 4; ++mi) {
        const int row0 = bm + wr * 64 + mi * 16 + ls * 4;
        #pragma unroll
        for (int ni = 0; ni < 2; ++ni) {
            const int col = bn + wc * 32 + ni * 16 + lr;
            const float bv = bias ? bias[col] : 0.0f;
            #pragma unroll
            for (int j = 0; j < 4; ++j) {
                const float v = acc[mi][ni][j] + bv;
                if (OUT_BF16)
                    ((unsigned short*)Cout)[(size_t)(row0 + j) * N + col] = f2bf(v);
                else
                    ((float*)Cout)[(size_t)(row0 + j) * N + col] = v;
            }
        }
    }
}

// ---------------------------------------------------------------------------
// Fused softmax + dynamic conv. One block per t (all 4 b, all 512 c).
// Phase 1: 64 softmax rows (b,head) from bf16 logits -> LDS [64][33] fp32.
// Phase 2: thread = (b, c0=8ch): 31-tap conv, h via L2 (XCD chunked swizzle),
//          weights broadcast from LDS. bf16 out.
// ---------------------------------------------------------------------------
__global__ __launch_bounds__(256) void dynconv_fused(const unsigned short* __restrict__ hb,
                                                     const unsigned short* __restrict__ logits,
                                                     unsigned short* __restrict__ cvb) {
    __shared__ float w_s[64][33];   // padded

    const int bid = blockIdx.x;
    const int t   = (bid & 7) * 256 + (bid >> 3);
    const int tid = threadIdx.x;

    // ---- Phase 1: softmax over K=31 for 64 rows, 4 lanes each ----
    {
        const int r = tid >> 2;          // row 0..63: b = r>>4, head = r&15
        const int q = tid & 3;           // lane-in-group
        const int b = r >> 4, hd = r & 15;
        const unsigned short* lp = logits + (size_t)(t * BB + b) * NPAD + hd * KK;
        float e[8];
        const int k0 = q * 8;
        const int kn = (q == 3) ? 7 : 8;
        float mx = -1e30f;
        #pragma unroll
        for (int j = 0; j < 8; ++j) {
            e[j] = (j < kn) ? bf2f(lp[k0 + j]) : -1e30f;
            mx = fmaxf(mx, e[j]);
        }
        mx = fmaxf(mx, __shfl_xor(mx, 1, 4));
        mx = fmaxf(mx, __shfl_xor(mx, 2, 4));
        float sm = 0.f;
        #pragma unroll
        for (int j = 0; j < 8; ++j) {
            e[j] = (j < kn) ? __expf(e[j] - mx) : 0.f;
            sm += e[j];
        }
        sm += __shfl_xor(sm, 1, 4);
        sm += __shfl_xor(sm, 2, 4);
        const float inv = 1.f / sm;
        #pragma unroll
        for (int j = 0; j < 8; ++j)
            if (j < kn) w_s[r][k0 + j] = e[j] * inv;
    }
    __syncthreads();

    // ---- Phase 2: conv ----
    const int c0 = (tid & 63) * 8;       // channel group; wave = one b
    const int b  = tid >> 6;
    const int wrow = b * 16 + (c0 >> 5); // (b, head)
    float acc[8] = {};
    #pragma unroll
    for (int k = 0; k < KK; ++k) {
        const int tt = t - PP + k;
        if ((unsigned)tt >= TT) continue;
        const ushort8 hv = *(const ushort8*)&hb[(size_t)((tt * BB + b) * CC) + c0];
        const float wk = w_s[wrow][k];
        #pragma unroll
        for (int j = 0; j < 8; ++j) acc[j] = fmaf(bf2f(hv[j]), wk, acc[j]);
    }
    ushort8 o;
    #pragma unroll
    for (int j = 0; j < 8; ++j) o[j] = f2bf(acc[j]);
    *(ushort8*)&cvb[(size_t)((t * BB + b) * CC) + c0] = o;
}

extern "C" void kernel_launch(void* const* d_in, const int* in_sizes, int n_in,
                              void* d_out, int out_size, void* d_ws, size_t ws_size,
                              hipStream_t stream) {
    const float* x  = (const float*)d_in[0];
    const float* W1 = (const float*)d_in[1];
    const float* b1 = (const float*)d_in[2];
    const float* Wl = (const float*)d_in[3];
    const float* W2 = (const float*)d_in[4];
    const float* b2 = (const float*)d_in[5];
    float* out = (float*)d_out;

    // workspace layout (all bf16 except out)
    unsigned short* xb  = (unsigned short*)d_ws;             // 8 MB
    unsigned short* hb  = xb  + (size_t)MM * CC;             // 8 MB
    unsigned short* cvb = hb  + (size_t)MM * CC;             // 8 MB
    unsigned short* W1b = cvb + (size_t)MM * CC;             // 0.5 MB
    unsigned short* Wlb = W1b + (size_t)CC * CC;             // 0.5 MB (padded)
    unsigned short* W2b = Wlb + (size_t)NPAD * CC;           // 0.5 MB
    unsigned short* lgb = W2b + (size_t)CC * CC;             // 8 MB bf16 logits

    const int nxc = MM * CC;           // 4194304

    cast_x<<<nxc / 1024, 256, 0, stream>>>(x, xb);
    cast_weights<<<768, 256, 0, stream>>>(W1, Wl, W2, W1b, Wlb, W2b);

    const int nblk = (MM / GBM) * (CC / GBN);   // 64 * 8 = 512

    // 1) h = x @ W1^T + b1   (bf16 out)
    gemm_nt_mfma<true><<<nblk, 256, 0, stream>>>(xb, W1b, b1, hb, CC, CC / GBN);
    // 2) logits = h @ Wl^T   (bf16 out, padded N)
    gemm_nt_mfma<true><<<nblk, 256, 0, stream>>>(hb, Wlb, nullptr, lgb, NPAD, NPAD / GBN);
    // 3+4) fused softmax + dynamic conv (bf16 out)
    dynconv_fused<<<TT, 256, 0, stream>>>(hb, lgb, cvb);
    // 5) out = cv @ W2^T + b2  (fp32 out)
    gemm_nt_mfma<false><<<nblk, 256, 0, stream>>>(cvb, W2b, b2, out, CC, CC / GBN);
}